// Round 1
// baseline (677.415 us; speedup 1.0000x reference)
//
#include <hip/hip_runtime.h>
#include <hip/hip_bf16.h>
#include <math.h>

#define N_NODES 50000
#define N_EDGES 400000
#define N_TOT   450000   /* edges + self loops */
#define HEADS   4
#define CHAN    128
#define HC      512
#define IN_DIM  5
#define HID     512
#define M_SEL   25000
#define NEG_SLOPE 0.2f

// ---------------------------------------------------------------------------
// Kernel 1: h = x @ W.T  [N, 512]; a_src/a_dst = einsum(h, att)  [N, 4]
// one wave per node, lane owns 8 contiguous channels (head = lane>>4)
// ---------------------------------------------------------------------------
__global__ void k_transform(const float* __restrict__ x, const float* __restrict__ W,
                            const float* __restrict__ att_src, const float* __restrict__ att_dst,
                            float* __restrict__ h, float* __restrict__ a_src,
                            float* __restrict__ a_dst) {
    __shared__ float sW[HC * IN_DIM];
    __shared__ float sas[HC], sad[HC];
    for (int i = threadIdx.x; i < HC * IN_DIM; i += 256) sW[i] = W[i];
    for (int i = threadIdx.x; i < HC; i += 256) { sas[i] = att_src[i]; sad[i] = att_dst[i]; }
    __syncthreads();

    int wave = threadIdx.x >> 6, lane = threadIdx.x & 63;
    int n = blockIdx.x * 4 + wave;
    if (n >= N_NODES) return;

    float xv[IN_DIM];
#pragma unroll
    for (int i = 0; i < IN_DIM; i++) xv[i] = x[n * IN_DIM + i];

    int c0 = lane * 8;
    float hv[8];
    float ps = 0.f, pd = 0.f;
#pragma unroll
    for (int j = 0; j < 8; j++) {
        int o = c0 + j;
        float acc = 0.f;
#pragma unroll
        for (int i = 0; i < IN_DIM; i++) acc += xv[i] * sW[o * IN_DIM + i];
        hv[j] = acc;
        ps += acc * sas[o];
        pd += acc * sad[o];
    }
    float4* hp = (float4*)(h + (size_t)n * HC + c0);
    hp[0] = make_float4(hv[0], hv[1], hv[2], hv[3]);
    hp[1] = make_float4(hv[4], hv[5], hv[6], hv[7]);

    // reduce within 16-lane head groups
#pragma unroll
    for (int off = 8; off >= 1; off >>= 1) {
        ps += __shfl_xor(ps, off);
        pd += __shfl_xor(pd, off);
    }
    if ((lane & 15) == 0) {
        int head = lane >> 4;
        a_src[n * HEADS + head] = ps;
        a_dst[n * HEADS + head] = pd;
    }
}

// ---------------------------------------------------------------------------
// CSR build: deg (init 1 for self loop) -> hist -> scan -> fill
// ---------------------------------------------------------------------------
__global__ void k_initdeg(int* __restrict__ deg) {
    int i = blockIdx.x * 256 + threadIdx.x;
    if (i < N_NODES) deg[i] = 1;
}

__global__ void k_hist(const int* __restrict__ ei, int* __restrict__ deg) {
    int e = blockIdx.x * 256 + threadIdx.x;
    if (e < N_EDGES) atomicAdd(&deg[ei[N_EDGES + e]], 1);
}

__global__ void k_scan1(const int* __restrict__ deg, int* __restrict__ excl,
                        int* __restrict__ bsum) {
    __shared__ int s[256];
    int i = blockIdx.x * 256 + threadIdx.x;
    int v = (i < N_NODES) ? deg[i] : 0;
    s[threadIdx.x] = v;
    __syncthreads();
    for (int off = 1; off < 256; off <<= 1) {
        int t = (threadIdx.x >= off) ? s[threadIdx.x - off] : 0;
        __syncthreads();
        s[threadIdx.x] += t;
        __syncthreads();
    }
    if (i < N_NODES) excl[i] = s[threadIdx.x] - v;
    if (threadIdx.x == 255) bsum[blockIdx.x] = s[255];
}

__global__ void k_scan2(int* __restrict__ bsum, int nb) {
    if (threadIdx.x == 0 && blockIdx.x == 0) {
        int acc = 0;
        for (int b = 0; b < nb; b++) { int v = bsum[b]; bsum[b] = acc; acc += v; }
    }
}

__global__ void k_scan3(int* __restrict__ excl, const int* __restrict__ bsum) {
    int i = blockIdx.x * 256 + threadIdx.x;
    if (i < N_NODES) excl[i] += bsum[blockIdx.x];
}

__global__ void k_fill_self(const int* __restrict__ offs, int* __restrict__ cursor,
                            int* __restrict__ csr) {
    int n = blockIdx.x * 256 + threadIdx.x;
    if (n < N_NODES) {
        int o = offs[n];
        csr[o] = n;            // self loop in slot 0
        cursor[n] = o + 1;
    }
}

__global__ void k_fill_edges(const int* __restrict__ ei, int* __restrict__ cursor,
                             int* __restrict__ csr) {
    int e = blockIdx.x * 256 + threadIdx.x;
    if (e < N_EDGES) {
        int d = ei[N_EDGES + e];
        int pos = atomicAdd(&cursor[d], 1);
        csr[pos] = ei[e];
    }
}

// ---------------------------------------------------------------------------
// Kernel: aggregate. One wave per dst node.
//   pass A: segment softmax stats (max & denom per head) via 16-lane groups
//   pass B: serial edge loop; wave gathers h[src] (2KB coalesced), fmax-acc.
// ---------------------------------------------------------------------------
__global__ void k_aggregate(const float* __restrict__ h, const float* __restrict__ a_src,
                            const float* __restrict__ a_dst, const int* __restrict__ csr,
                            const int* __restrict__ offs, const int* __restrict__ deg,
                            const float* __restrict__ bias, float* __restrict__ emb) {
    int wave = threadIdx.x >> 6, lane = threadIdx.x & 63;
    int n = blockIdx.x * 4 + wave;
    if (n >= N_NODES) return;

    int base = offs[n];
    int dn = deg[n];
    int head = lane >> 4;
    float adn = a_dst[n * HEADS + head];

    // pass A1: per-head max. lane handles edge (lane&15) + 16*chunk for its head.
    float m = -INFINITY;
    for (int e0 = 0; e0 < dn; e0 += 16) {
        int e = e0 + (lane & 15);
        if (e < dn) {
            int s = csr[base + e];
            float t = a_src[s * HEADS + head] + adn;
            t = (t > 0.f) ? t : NEG_SLOPE * t;
            m = fmaxf(m, t);
        }
    }
#pragma unroll
    for (int off = 8; off >= 1; off >>= 1) m = fmaxf(m, __shfl_xor(m, off));

    // pass A2: denom
    float den = 0.f;
    for (int e0 = 0; e0 < dn; e0 += 16) {
        int e = e0 + (lane & 15);
        if (e < dn) {
            int s = csr[base + e];
            float t = a_src[s * HEADS + head] + adn;
            t = (t > 0.f) ? t : NEG_SLOPE * t;
            den += __expf(t - m);
        }
    }
#pragma unroll
    for (int off = 8; off >= 1; off >>= 1) den += __shfl_xor(den, off);
    float invden = 1.0f / den;

    // pass B: weighted scatter-max over this node's edges
    float acc[8];
#pragma unroll
    for (int j = 0; j < 8; j++) acc[j] = -INFINITY;
    int c0 = lane * 8;  // head of these channels == lane>>4 == head  (consistent)

    for (int e = 0; e < dn; e++) {
        int s = csr[base + e];
        float t = a_src[s * HEADS + head] + adn;
        t = (t > 0.f) ? t : NEG_SLOPE * t;
        float attn = __expf(t - m) * invden;
        const float4* hp = (const float4*)(h + (size_t)s * HC + c0);
        float4 h0 = hp[0], h1 = hp[1];
        acc[0] = fmaxf(acc[0], h0.x * attn);
        acc[1] = fmaxf(acc[1], h0.y * attn);
        acc[2] = fmaxf(acc[2], h0.z * attn);
        acc[3] = fmaxf(acc[3], h0.w * attn);
        acc[4] = fmaxf(acc[4], h1.x * attn);
        acc[5] = fmaxf(acc[5], h1.y * attn);
        acc[6] = fmaxf(acc[6], h1.z * attn);
        acc[7] = fmaxf(acc[7], h1.w * attn);
    }

    float4 b0 = *(const float4*)(bias + c0);
    float4 b1 = *(const float4*)(bias + c0 + 4);
    float4* op = (float4*)(emb + (size_t)n * HC + c0);
    op[0] = make_float4(acc[0] + b0.x, acc[1] + b0.y, acc[2] + b0.z, acc[3] + b0.w);
    op[1] = make_float4(acc[4] + b1.x, acc[5] + b1.y, acc[6] + b1.z, acc[7] + b1.w);
}

// ---------------------------------------------------------------------------
// fp32 tiled GEMM:  C[m,o] = act( sum_k A[m,k] * Wt[o,k] + bias[o] )
// BM=BN=64, BK=16, 256 threads, 4x4 microtile. GATHER fuses TEAM_IDX row map.
// ---------------------------------------------------------------------------
template <bool GATHER>
__global__ void k_gemm_relu(const float* __restrict__ A, const float* __restrict__ Wt,
                            const float* __restrict__ bias, float* __restrict__ C, int M) {
    __shared__ float As[16][64];
    __shared__ float Bs[16][64];
    int tid = threadIdx.x;
    int m0 = blockIdx.y * 64;
    int o0 = blockIdx.x * 64;
    int tm = tid >> 4, tn = tid & 15;
    int lr = tid >> 2;           // row in tile, 0..63
    int lk = (tid & 3) * 4;      // k offset in tile

    float acc[4][4] = {{0.f}};

    for (int k0 = 0; k0 < HC; k0 += 16) {
        int m = m0 + lr;
        float4 av = make_float4(0.f, 0.f, 0.f, 0.f);
        if (m < M) {
            int row = GATHER ? (((m >> 2) << 3) + (m & 3)) : m;
            av = *(const float4*)(A + (size_t)row * HC + k0 + lk);
        }
        float4 bv = *(const float4*)(Wt + (size_t)(o0 + lr) * HC + k0 + lk);
        __syncthreads();
        As[lk + 0][lr] = av.x; As[lk + 1][lr] = av.y;
        As[lk + 2][lr] = av.z; As[lk + 3][lr] = av.w;
        Bs[lk + 0][lr] = bv.x; Bs[lk + 1][lr] = bv.y;
        Bs[lk + 2][lr] = bv.z; Bs[lk + 3][lr] = bv.w;
        __syncthreads();
#pragma unroll
        for (int k = 0; k < 16; k++) {
            float4 a = *(const float4*)&As[k][tm * 4];
            float4 b = *(const float4*)&Bs[k][tn * 4];
            float ar[4] = {a.x, a.y, a.z, a.w};
            float br[4] = {b.x, b.y, b.z, b.w};
#pragma unroll
            for (int i = 0; i < 4; i++)
#pragma unroll
                for (int j = 0; j < 4; j++) acc[i][j] += ar[i] * br[j];
        }
    }

    float4 bv = *(const float4*)(bias + o0 + tn * 4);
    float bb[4] = {bv.x, bv.y, bv.z, bv.w};
#pragma unroll
    for (int i = 0; i < 4; i++) {
        int m = m0 + tm * 4 + i;
        if (m < M) {
            float4 v = make_float4(fmaxf(acc[i][0] + bb[0], 0.f),
                                   fmaxf(acc[i][1] + bb[1], 0.f),
                                   fmaxf(acc[i][2] + bb[2], 0.f),
                                   fmaxf(acc[i][3] + bb[3], 0.f));
            *(float4*)(C + (size_t)m * HC + o0 + tn * 4) = v;
        }
    }
}

// ---------------------------------------------------------------------------
// Final layer: out[m, 0..1] = tanh(h2[m] . W3[o] + b3[o]); one wave per row
// ---------------------------------------------------------------------------
__global__ void k_final(const float* __restrict__ h2, const float* __restrict__ W3,
                        const float* __restrict__ b3, float* __restrict__ out, int M) {
    int wave = threadIdx.x >> 6, lane = threadIdx.x & 63;
    int m = blockIdx.x * 4 + wave;
    if (m >= M) return;
    float s0 = 0.f, s1 = 0.f;
    for (int k = lane; k < HID; k += 64) {
        float v = h2[(size_t)m * HID + k];
        s0 += v * W3[k];
        s1 += v * W3[HID + k];
    }
#pragma unroll
    for (int off = 32; off >= 1; off >>= 1) {
        s0 += __shfl_xor(s0, off);
        s1 += __shfl_xor(s1, off);
    }
    if (lane == 0) {
        out[(size_t)m * 2 + 0] = tanhf(s0 + b3[0]);
        out[(size_t)m * 2 + 1] = tanhf(s1 + b3[1]);
    }
}

// ---------------------------------------------------------------------------
extern "C" void kernel_launch(void* const* d_in, const int* in_sizes, int n_in,
                              void* d_out, int out_size, void* d_ws, size_t ws_size,
                              hipStream_t stream) {
    const float* x       = (const float*)d_in[0];
    const int*   ei      = (const int*)d_in[1];   // [2, E] int32
    const float* W       = (const float*)d_in[3];
    const float* att_src = (const float*)d_in[4];
    const float* att_dst = (const float*)d_in[5];
    const float* bias    = (const float*)d_in[6];
    const float* W1      = (const float*)d_in[7];
    const float* b1      = (const float*)d_in[8];
    const float* W2      = (const float*)d_in[9];
    const float* b2      = (const float*)d_in[10];
    const float* W3      = (const float*)d_in[11];
    const float* b3      = (const float*)d_in[12];
    float* out = (float*)d_out;

    char* ws = (char*)d_ws;
    // layout (bytes):
    float* h     = (float*)(ws);                  // 102,400,000  [N,512]
    float* emb   = (float*)(ws + 102400000);      // 102,400,000  [N,512]
    float* a_src = (float*)(ws + 204800000);      //     800,000  [N,4]
    float* a_dst = (float*)(ws + 205600000);      //     800,000
    int*   deg   = (int*)  (ws + 206400000);      //     200,000
    int*   offs  = (int*)  (ws + 206600000);      //     200,000
    int*   curs  = (int*)  (ws + 206800000);      //     200,000
    int*   bsum  = (int*)  (ws + 207000000);      //       1,024
    int*   csr   = (int*)  (ws + 207001024);      //   1,800,000   (end ~208.8 MB)
    float* h1 = h;                                // reuse: h dead after aggregate
    float* h2 = h + (size_t)M_SEL * HID;          // 25000*512 floats each

    k_transform<<<12500, 256, 0, stream>>>(x, W, att_src, att_dst, h, a_src, a_dst);
    k_initdeg<<<(N_NODES + 255) / 256, 256, 0, stream>>>(deg);
    k_hist<<<(N_EDGES + 255) / 256, 256, 0, stream>>>(ei, deg);
    k_scan1<<<196, 256, 0, stream>>>(deg, offs, bsum);
    k_scan2<<<1, 64, 0, stream>>>(bsum, 196);
    k_scan3<<<196, 256, 0, stream>>>(offs, bsum);
    k_fill_self<<<(N_NODES + 255) / 256, 256, 0, stream>>>(offs, curs, csr);
    k_fill_edges<<<(N_EDGES + 255) / 256, 256, 0, stream>>>(ei, curs, csr);
    k_aggregate<<<12500, 256, 0, stream>>>(h, a_src, a_dst, csr, offs, deg, bias, emb);

    dim3 g1(8, (M_SEL + 63) / 64);
    k_gemm_relu<true><<<g1, 256, 0, stream>>>(emb, W1, b1, h1, M_SEL);
    k_gemm_relu<false><<<g1, 256, 0, stream>>>(h1, W2, b2, h2, M_SEL);
    k_final<<<(M_SEL + 3) / 4, 256, 0, stream>>>(h2, W3, b3, out, M_SEL);
}

// Round 2
// 269.231 us; speedup vs baseline: 2.5161x; 2.5161x over previous
//
#include <hip/hip_runtime.h>
#include <hip/hip_bf16.h>
#include <math.h>

#define N_NODES 50000
#define N_EDGES 400000
#define HEADS   4
#define HC      512
#define IN_DIM  5
#define M_SEL   25000
#define NEG_SLOPE 0.2f

typedef __attribute__((ext_vector_type(8))) short bf16x8;
typedef __attribute__((ext_vector_type(4))) float f32x4;

__device__ inline unsigned short f2bf(float f) {
    union { float f; unsigned u; } v; v.f = f;
    unsigned r = v.u + 0x7FFF + ((v.u >> 16) & 1);   // RNE
    return (unsigned short)(r >> 16);
}
__device__ inline float bf2f(unsigned short b) {
    union { unsigned u; float f; } v; v.u = ((unsigned)b) << 16;
    return v.f;
}

// ---------------------------------------------------------------------------
// fp32 -> bf16 weight conversion (float4 / 4 elems per thread)
// ---------------------------------------------------------------------------
__global__ void k_cvt(const float* __restrict__ src, unsigned short* __restrict__ dst, int n4) {
    int i = blockIdx.x * 256 + threadIdx.x;
    if (i < n4) {
        float4 v = ((const float4*)src)[i];
        ushort4 o;
        o.x = f2bf(v.x); o.y = f2bf(v.y); o.z = f2bf(v.z); o.w = f2bf(v.w);
        ((ushort4*)dst)[i] = o;
    }
}

// ---------------------------------------------------------------------------
// Kernel 1: h = x @ W.T  [N, 512] (bf16 out); a_src/a_dst einsum  [N, 4] f32
// one wave per node, lane owns 8 contiguous channels (head = lane>>4)
// ---------------------------------------------------------------------------
__global__ void k_transform(const float* __restrict__ x, const float* __restrict__ W,
                            const float* __restrict__ att_src, const float* __restrict__ att_dst,
                            unsigned short* __restrict__ h, float* __restrict__ a_src,
                            float* __restrict__ a_dst) {
    __shared__ float sW[HC * IN_DIM];
    __shared__ float sas[HC], sad[HC];
    for (int i = threadIdx.x; i < HC * IN_DIM; i += 256) sW[i] = W[i];
    for (int i = threadIdx.x; i < HC; i += 256) { sas[i] = att_src[i]; sad[i] = att_dst[i]; }
    __syncthreads();

    int wave = threadIdx.x >> 6, lane = threadIdx.x & 63;
    int n = blockIdx.x * 4 + wave;
    if (n >= N_NODES) return;

    float xv[IN_DIM];
#pragma unroll
    for (int i = 0; i < IN_DIM; i++) xv[i] = x[n * IN_DIM + i];

    int c0 = lane * 8;
    float ps = 0.f, pd = 0.f;
    bf16x8 hv8;
#pragma unroll
    for (int j = 0; j < 8; j++) {
        int o = c0 + j;
        float acc = 0.f;
#pragma unroll
        for (int i = 0; i < IN_DIM; i++) acc += xv[i] * sW[o * IN_DIM + i];
        hv8[j] = (short)f2bf(acc);
        ps += acc * sas[o];
        pd += acc * sad[o];
    }
    *(bf16x8*)(h + (size_t)n * HC + c0) = hv8;

#pragma unroll
    for (int off = 8; off >= 1; off >>= 1) {
        ps += __shfl_xor(ps, off);
        pd += __shfl_xor(pd, off);
    }
    if ((lane & 15) == 0) {
        int head = lane >> 4;
        a_src[n * HEADS + head] = ps;
        a_dst[n * HEADS + head] = pd;
    }
}

// ---------------------------------------------------------------------------
// CSR build: deg (init 1 for self loop) -> hist -> scan -> fill
// ---------------------------------------------------------------------------
__global__ void k_initdeg(int* __restrict__ deg) {
    int i = blockIdx.x * 256 + threadIdx.x;
    if (i < N_NODES) deg[i] = 1;
}

__global__ void k_hist(const int* __restrict__ ei, int* __restrict__ deg) {
    int e = blockIdx.x * 256 + threadIdx.x;
    if (e < N_EDGES) atomicAdd(&deg[ei[N_EDGES + e]], 1);
}

__global__ void k_scan1(const int* __restrict__ deg, int* __restrict__ excl,
                        int* __restrict__ bsum) {
    __shared__ int s[256];
    int i = blockIdx.x * 256 + threadIdx.x;
    int v = (i < N_NODES) ? deg[i] : 0;
    s[threadIdx.x] = v;
    __syncthreads();
    for (int off = 1; off < 256; off <<= 1) {
        int t = (threadIdx.x >= off) ? s[threadIdx.x - off] : 0;
        __syncthreads();
        s[threadIdx.x] += t;
        __syncthreads();
    }
    if (i < N_NODES) excl[i] = s[threadIdx.x] - v;
    if (threadIdx.x == 255) bsum[blockIdx.x] = s[255];
}

__global__ void k_scan2(int* __restrict__ bsum, int nb) {
    if (threadIdx.x == 0 && blockIdx.x == 0) {
        int acc = 0;
        for (int b = 0; b < nb; b++) { int v = bsum[b]; bsum[b] = acc; acc += v; }
    }
}

__global__ void k_scan3(int* __restrict__ excl, const int* __restrict__ bsum) {
    int i = blockIdx.x * 256 + threadIdx.x;
    if (i < N_NODES) excl[i] += bsum[blockIdx.x];
}

__global__ void k_fill_self(const int* __restrict__ offs, int* __restrict__ cursor,
                            int* __restrict__ csr) {
    int n = blockIdx.x * 256 + threadIdx.x;
    if (n < N_NODES) {
        int o = offs[n];
        csr[o] = n;
        cursor[n] = o + 1;
    }
}

__global__ void k_fill_edges(const int* __restrict__ ei, int* __restrict__ cursor,
                             int* __restrict__ csr) {
    int e = blockIdx.x * 256 + threadIdx.x;
    if (e < N_EDGES) {
        int d = ei[N_EDGES + e];
        int pos = atomicAdd(&cursor[d], 1);
        csr[pos] = ei[e];
    }
}

// ---------------------------------------------------------------------------
// Aggregate — TEAM NODES ONLY (emb of non-team nodes is never consumed).
// One wave per team dst node. Softmax stats via 16-lane groups, then serial
// edge loop with coalesced 1KB bf16 gather of h[src], weighted fmax-accum.
// Writes compact emb_sel[w] (bf16) so the MLP needs no gather.
// ---------------------------------------------------------------------------
__global__ void k_aggregate(const unsigned short* __restrict__ h, const float* __restrict__ a_src,
                            const float* __restrict__ a_dst, const int* __restrict__ csr,
                            const int* __restrict__ offs, const int* __restrict__ deg,
                            const float* __restrict__ bias, unsigned short* __restrict__ emb_sel) {
    int wave = threadIdx.x >> 6, lane = threadIdx.x & 63;
    int w = blockIdx.x * 4 + wave;
    if (w >= M_SEL) return;
    int n = ((w >> 2) << 3) + (w & 3);   // TEAM_IDX[w]

    int base = offs[n];
    int dn = deg[n];
    int head = lane >> 4;
    float adn = a_dst[n * HEADS + head];

    // per-head max
    float m = -INFINITY;
    for (int e0 = 0; e0 < dn; e0 += 16) {
        int e = e0 + (lane & 15);
        if (e < dn) {
            int s = csr[base + e];
            float t = a_src[s * HEADS + head] + adn;
            t = (t > 0.f) ? t : NEG_SLOPE * t;
            m = fmaxf(m, t);
        }
    }
#pragma unroll
    for (int off = 8; off >= 1; off >>= 1) m = fmaxf(m, __shfl_xor(m, off));

    // denom
    float den = 0.f;
    for (int e0 = 0; e0 < dn; e0 += 16) {
        int e = e0 + (lane & 15);
        if (e < dn) {
            int s = csr[base + e];
            float t = a_src[s * HEADS + head] + adn;
            t = (t > 0.f) ? t : NEG_SLOPE * t;
            den += __expf(t - m);
        }
    }
#pragma unroll
    for (int off = 8; off >= 1; off >>= 1) den += __shfl_xor(den, off);
    float invden = 1.0f / den;

    // weighted scatter-max
    float acc[8];
#pragma unroll
    for (int j = 0; j < 8; j++) acc[j] = -INFINITY;
    int c0 = lane * 8;   // channel head == lane>>4 == head

    for (int e = 0; e < dn; e++) {
        int s = csr[base + e];
        float t = a_src[s * HEADS + head] + adn;
        t = (t > 0.f) ? t : NEG_SLOPE * t;
        float attn = __expf(t - m) * invden;
        bf16x8 hv = *(const bf16x8*)(h + (size_t)s * HC + c0);
#pragma unroll
        for (int j = 0; j < 8; j++)
            acc[j] = fmaxf(acc[j], bf2f((unsigned short)hv[j]) * attn);
    }

    bf16x8 ov;
#pragma unroll
    for (int j = 0; j < 8; j++) ov[j] = (short)f2bf(acc[j] + bias[c0 + j]);
    *(bf16x8*)(emb_sel + (size_t)w * HC + c0) = ov;
}

// ---------------------------------------------------------------------------
// bf16 MFMA GEMM:  C[m,o] = relu( sum_k A[m,k]*Wt[o,k] + bias[o] ) -> bf16
// 128x128 tile, BK=64, 256 threads (2x2 waves, 64x64/wave, 4x4 frags of
// 16x16x32). LDS rows padded to 72 shorts (144B: 2-way bank alias = free).
// Reg-staged prefetch: next tile's global loads overlap current MFMAs.
// ---------------------------------------------------------------------------
#define BK  64
#define LDK 72

template <bool RELU>
__global__ __launch_bounds__(256) void k_gemm(const unsigned short* __restrict__ A, int M,
                                              const unsigned short* __restrict__ Wt,
                                              const float* __restrict__ bias,
                                              unsigned short* __restrict__ C) {
    __shared__ unsigned short As[128 * LDK];
    __shared__ unsigned short Bs[128 * LDK];
    int tid = threadIdx.x;
    int m0 = blockIdx.y * 128;
    int o0 = blockIdx.x * 128;
    int wv = tid >> 6, lane = tid & 63;
    int wm = wv >> 1, wn = wv & 1;

    f32x4 acc[4][4];
#pragma unroll
    for (int i = 0; i < 4; i++)
#pragma unroll
        for (int j = 0; j < 4; j++) acc[i][j] = (f32x4){0.f, 0.f, 0.f, 0.f};

    bf16x8 ra[4], rb[4];
    // prefetch k0 = 0
#pragma unroll
    for (int s = 0; s < 4; s++) {
        int c = s * 256 + tid;
        int row = c >> 3, col = (c & 7) * 8;
        int m = m0 + row;
        bf16x8 av = {0, 0, 0, 0, 0, 0, 0, 0};
        if (m < M) av = *(const bf16x8*)(A + (size_t)m * HC + col);
        ra[s] = av;
        rb[s] = *(const bf16x8*)(Wt + (size_t)(o0 + row) * HC + col);
    }

    for (int k0 = 0; k0 < HC; k0 += BK) {
        __syncthreads();
#pragma unroll
        for (int s = 0; s < 4; s++) {
            int c = s * 256 + tid;
            int row = c >> 3, col = (c & 7) * 8;
            *(bf16x8*)(&As[row * LDK + col]) = ra[s];
            *(bf16x8*)(&Bs[row * LDK + col]) = rb[s];
        }
        __syncthreads();

        int kn = k0 + BK;
        if (kn < HC) {
#pragma unroll
            for (int s = 0; s < 4; s++) {
                int c = s * 256 + tid;
                int row = c >> 3, col = (c & 7) * 8;
                int m = m0 + row;
                bf16x8 av = {0, 0, 0, 0, 0, 0, 0, 0};
                if (m < M) av = *(const bf16x8*)(A + (size_t)m * HC + kn + col);
                ra[s] = av;
                rb[s] = *(const bf16x8*)(Wt + (size_t)(o0 + row) * HC + kn + col);
            }
        }

#pragma unroll
        for (int kk = 0; kk < 2; kk++) {
            int kb = kk * 32 + (lane >> 4) * 8;
            bf16x8 af[4], bfr[4];
#pragma unroll
            for (int mi = 0; mi < 4; mi++)
                af[mi] = *(const bf16x8*)(&As[(wm * 64 + mi * 16 + (lane & 15)) * LDK + kb]);
#pragma unroll
            for (int ni = 0; ni < 4; ni++)
                bfr[ni] = *(const bf16x8*)(&Bs[(wn * 64 + ni * 16 + (lane & 15)) * LDK + kb]);
#pragma unroll
            for (int mi = 0; mi < 4; mi++)
#pragma unroll
                for (int ni = 0; ni < 4; ni++)
                    acc[mi][ni] = __builtin_amdgcn_mfma_f32_16x16x32_bf16(
                        af[mi], bfr[ni], acc[mi][ni], 0, 0, 0);
        }
    }

#pragma unroll
    for (int ni = 0; ni < 4; ni++) {
        int ncol = o0 + wn * 64 + ni * 16 + (lane & 15);
        float bv = bias[ncol];
#pragma unroll
        for (int mi = 0; mi < 4; mi++) {
            int mbase = m0 + wm * 64 + mi * 16 + (lane >> 4) * 4;
#pragma unroll
            for (int r = 0; r < 4; r++) {
                int m = mbase + r;
                if (m < M) {
                    float v = acc[mi][ni][r] + bv;
                    if (RELU) v = fmaxf(v, 0.f);
                    C[(size_t)m * HC + ncol] = f2bf(v);
                }
            }
        }
    }
}

// ---------------------------------------------------------------------------
// Final layer: out[m, 0..1] = tanh(h2[m] . W3[o] + b3[o]); one wave per row
// ---------------------------------------------------------------------------
__global__ void k_final(const unsigned short* __restrict__ h2, const float* __restrict__ W3,
                        const float* __restrict__ b3, float* __restrict__ out, int M) {
    int wave = threadIdx.x >> 6, lane = threadIdx.x & 63;
    int m = blockIdx.x * 4 + wave;
    if (m >= M) return;
    float s0 = 0.f, s1 = 0.f;
    bf16x8 hv = *(const bf16x8*)(h2 + (size_t)m * HC + lane * 8);
#pragma unroll
    for (int j = 0; j < 8; j++) {
        int k = lane * 8 + j;
        float v = bf2f((unsigned short)hv[j]);
        s0 += v * W3[k];
        s1 += v * W3[HC + k];
    }
#pragma unroll
    for (int off = 32; off >= 1; off >>= 1) {
        s0 += __shfl_xor(s0, off);
        s1 += __shfl_xor(s1, off);
    }
    if (lane == 0) {
        out[(size_t)m * 2 + 0] = tanhf(s0 + b3[0]);
        out[(size_t)m * 2 + 1] = tanhf(s1 + b3[1]);
    }
}

// ---------------------------------------------------------------------------
extern "C" void kernel_launch(void* const* d_in, const int* in_sizes, int n_in,
                              void* d_out, int out_size, void* d_ws, size_t ws_size,
                              hipStream_t stream) {
    const float* x       = (const float*)d_in[0];
    const int*   ei      = (const int*)d_in[1];
    const float* W       = (const float*)d_in[3];
    const float* att_src = (const float*)d_in[4];
    const float* att_dst = (const float*)d_in[5];
    const float* bias    = (const float*)d_in[6];
    const float* W1      = (const float*)d_in[7];
    const float* b1      = (const float*)d_in[8];
    const float* W2      = (const float*)d_in[9];
    const float* b2      = (const float*)d_in[10];
    const float* W3      = (const float*)d_in[11];
    const float* b3      = (const float*)d_in[12];
    float* out = (float*)d_out;

    char* ws = (char*)d_ws;
    unsigned short* h       = (unsigned short*)(ws);               // 51,200,000
    unsigned short* emb_sel = (unsigned short*)(ws + 51200000);    // 25,600,000
    unsigned short* h1      = (unsigned short*)(ws + 76800000);    // 25,600,000
    unsigned short* h2      = (unsigned short*)(ws + 102400000);   // 25,600,000
    unsigned short* W1b     = (unsigned short*)(ws + 128000000);   //    524,288
    unsigned short* W2b     = (unsigned short*)(ws + 128524288);   //    524,288
    float* a_src = (float*)(ws + 129048576);                       //    800,000
    float* a_dst = (float*)(ws + 129848576);                       //    800,000
    int*   deg   = (int*)  (ws + 130648576);                       //    200,000
    int*   offs  = (int*)  (ws + 130848576);                       //    200,000
    int*   curs  = (int*)  (ws + 131048576);                       //    200,000
    int*   bsum  = (int*)  (ws + 131248576);                       //      1,024
    int*   csr   = (int*)  (ws + 131249600);                       //  1,800,000  (~133 MB)

    k_cvt<<<256, 256, 0, stream>>>(W1, W1b, 65536);
    k_cvt<<<256, 256, 0, stream>>>(W2, W2b, 65536);
    k_transform<<<12500, 256, 0, stream>>>(x, W, att_src, att_dst, h, a_src, a_dst);
    k_initdeg<<<(N_NODES + 255) / 256, 256, 0, stream>>>(deg);
    k_hist<<<(N_EDGES + 255) / 256, 256, 0, stream>>>(ei, deg);
    k_scan1<<<196, 256, 0, stream>>>(deg, offs, bsum);
    k_scan2<<<1, 64, 0, stream>>>(bsum, 196);
    k_scan3<<<196, 256, 0, stream>>>(offs, bsum);
    k_fill_self<<<(N_NODES + 255) / 256, 256, 0, stream>>>(offs, curs, csr);
    k_fill_edges<<<(N_EDGES + 255) / 256, 256, 0, stream>>>(ei, curs, csr);
    k_aggregate<<<6250, 256, 0, stream>>>(h, a_src, a_dst, csr, offs, deg, bias, emb_sel);

    dim3 g(4, 196);
    k_gemm<true><<<g, 256, 0, stream>>>(emb_sel, M_SEL, W1b, b1, h1);
    k_gemm<true><<<g, 256, 0, stream>>>(h1, M_SEL, W2b, b2, h2);
    k_final<<<(M_SEL + 3) / 4, 256, 0, stream>>>(h2, W3, b3, out, M_SEL);
}

// Round 3
// 232.519 us; speedup vs baseline: 2.9134x; 1.1579x over previous
//
#include <hip/hip_runtime.h>
#include <hip/hip_bf16.h>
#include <math.h>

#define N_NODES 50000
#define N_EDGES 400000
#define HEADS   4
#define HC      512
#define IN_DIM  5
#define M_SEL   25000
#define NEG_SLOPE 0.2f

typedef __attribute__((ext_vector_type(8))) short bf16x8;
typedef __attribute__((ext_vector_type(4))) float f32x4;

__device__ inline unsigned short f2bf(float f) {
    union { float f; unsigned u; } v; v.f = f;
    unsigned r = v.u + 0x7FFF + ((v.u >> 16) & 1);   // RNE
    return (unsigned short)(r >> 16);
}
__device__ inline float bf2f(unsigned short b) {
    union { unsigned u; float f; } v; v.u = ((unsigned)b) << 16;
    return v.f;
}

// ---------------------------------------------------------------------------
// fp32 -> bf16 weight conversion
// ---------------------------------------------------------------------------
__global__ void k_cvt(const float* __restrict__ src, unsigned short* __restrict__ dst, int n4) {
    int i = blockIdx.x * 256 + threadIdx.x;
    if (i < n4) {
        float4 v = ((const float4*)src)[i];
        ushort4 o;
        o.x = f2bf(v.x); o.y = f2bf(v.y); o.z = f2bf(v.z); o.w = f2bf(v.w);
        ((ushort4*)dst)[i] = o;
    }
}

// ---------------------------------------------------------------------------
// Kernel 1: h = x @ W.T  [N, 512] (bf16); a_src/a_dst einsum [N, 4] f32.
// No LDS (R2: sW reads were 8-way bank-conflicted, 1.7e7 conflict cycles).
// Lane owns 8 contiguous channels; its 40 W floats = 160 contiguous bytes ->
// 10 float4 register loads, L2-hot. 8 nodes per wave amortize the load.
// ---------------------------------------------------------------------------
#define TR_NPW 8   /* nodes per wave */

__global__ __launch_bounds__(256) void k_transform(
        const float* __restrict__ x, const float* __restrict__ W,
        const float* __restrict__ att_src, const float* __restrict__ att_dst,
        unsigned short* __restrict__ h, float* __restrict__ a_src,
        float* __restrict__ a_dst) {
    int wave = threadIdx.x >> 6, lane = threadIdx.x & 63;
    int c0 = lane * 8;

    float wreg[40];
    const float4* wp = (const float4*)(W + c0 * IN_DIM);
#pragma unroll
    for (int i = 0; i < 10; i++) ((float4*)wreg)[i] = wp[i];
    float sas[8], sad[8];
    *(float4*)&sas[0] = *(const float4*)(att_src + c0);
    *(float4*)&sas[4] = *(const float4*)(att_src + c0 + 4);
    *(float4*)&sad[0] = *(const float4*)(att_dst + c0);
    *(float4*)&sad[4] = *(const float4*)(att_dst + c0 + 4);

    int n0 = (blockIdx.x * 4 + wave) * TR_NPW;
#pragma unroll
    for (int t = 0; t < TR_NPW; t++) {
        int n = n0 + t;
        if (n >= N_NODES) return;
        float xv[IN_DIM];
#pragma unroll
        for (int i = 0; i < IN_DIM; i++) xv[i] = x[n * IN_DIM + i];

        float ps = 0.f, pd = 0.f;
        bf16x8 hv8;
#pragma unroll
        for (int j = 0; j < 8; j++) {
            float acc = 0.f;
#pragma unroll
            for (int i = 0; i < IN_DIM; i++) acc += xv[i] * wreg[j * IN_DIM + i];
            hv8[j] = (short)f2bf(acc);
            ps += acc * sas[j];
            pd += acc * sad[j];
        }
        *(bf16x8*)(h + (size_t)n * HC + c0) = hv8;

#pragma unroll
        for (int off = 8; off >= 1; off >>= 1) {
            ps += __shfl_xor(ps, off);
            pd += __shfl_xor(pd, off);
        }
        if ((lane & 15) == 0) {
            int head = lane >> 4;
            a_src[n * HEADS + head] = ps;
            a_dst[n * HEADS + head] = pd;
        }
    }
}

// ---------------------------------------------------------------------------
// CSR build: deg (init 1 for self loop) -> hist -> scan -> fill
// ---------------------------------------------------------------------------
__global__ void k_initdeg(int* __restrict__ deg) {
    int i = blockIdx.x * 256 + threadIdx.x;
    if (i < N_NODES) deg[i] = 1;
}

__global__ void k_hist(const int* __restrict__ ei, int* __restrict__ deg) {
    int e = blockIdx.x * 256 + threadIdx.x;
    if (e < N_EDGES) atomicAdd(&deg[ei[N_EDGES + e]], 1);
}

__global__ void k_scan1(const int* __restrict__ deg, int* __restrict__ excl,
                        int* __restrict__ bsum) {
    __shared__ int s[256];
    int i = blockIdx.x * 256 + threadIdx.x;
    int v = (i < N_NODES) ? deg[i] : 0;
    s[threadIdx.x] = v;
    __syncthreads();
    for (int off = 1; off < 256; off <<= 1) {
        int t = (threadIdx.x >= off) ? s[threadIdx.x - off] : 0;
        __syncthreads();
        s[threadIdx.x] += t;
        __syncthreads();
    }
    if (i < N_NODES) excl[i] = s[threadIdx.x] - v;
    if (threadIdx.x == 255) bsum[blockIdx.x] = s[255];
}

__global__ void k_scan2(int* __restrict__ bsum, int nb) {
    if (threadIdx.x == 0 && blockIdx.x == 0) {
        int acc = 0;
        for (int b = 0; b < nb; b++) { int v = bsum[b]; bsum[b] = acc; acc += v; }
    }
}

__global__ void k_scan3(int* __restrict__ excl, const int* __restrict__ bsum) {
    int i = blockIdx.x * 256 + threadIdx.x;
    if (i < N_NODES) excl[i] += bsum[blockIdx.x];
}

__global__ void k_fill_self(const int* __restrict__ offs, int* __restrict__ cursor,
                            int* __restrict__ csr) {
    int n = blockIdx.x * 256 + threadIdx.x;
    if (n < N_NODES) {
        int o = offs[n];
        csr[o] = n;
        cursor[n] = o + 1;
    }
}

__global__ void k_fill_edges(const int* __restrict__ ei, int* __restrict__ cursor,
                             int* __restrict__ csr) {
    int e = blockIdx.x * 256 + threadIdx.x;
    if (e < N_EDGES) {
        int d = ei[N_EDGES + e];
        int pos = atomicAdd(&cursor[d], 1);
        csr[pos] = ei[e];
    }
}

// ---------------------------------------------------------------------------
// Aggregate — TEAM NODES ONLY. One wave per team dst node.
// ---------------------------------------------------------------------------
__global__ void k_aggregate(const unsigned short* __restrict__ h, const float* __restrict__ a_src,
                            const float* __restrict__ a_dst, const int* __restrict__ csr,
                            const int* __restrict__ offs, const int* __restrict__ deg,
                            const float* __restrict__ bias, unsigned short* __restrict__ emb_sel) {
    int wave = threadIdx.x >> 6, lane = threadIdx.x & 63;
    int w = blockIdx.x * 4 + wave;
    if (w >= M_SEL) return;
    int n = ((w >> 2) << 3) + (w & 3);   // TEAM_IDX[w]

    int base = offs[n];
    int dn = deg[n];
    int head = lane >> 4;
    float adn = a_dst[n * HEADS + head];

    // per-head max
    float m = -INFINITY;
    for (int e0 = 0; e0 < dn; e0 += 16) {
        int e = e0 + (lane & 15);
        if (e < dn) {
            int s = csr[base + e];
            float t = a_src[s * HEADS + head] + adn;
            t = (t > 0.f) ? t : NEG_SLOPE * t;
            m = fmaxf(m, t);
        }
    }
#pragma unroll
    for (int off = 8; off >= 1; off >>= 1) m = fmaxf(m, __shfl_xor(m, off));

    // denom
    float den = 0.f;
    for (int e0 = 0; e0 < dn; e0 += 16) {
        int e = e0 + (lane & 15);
        if (e < dn) {
            int s = csr[base + e];
            float t = a_src[s * HEADS + head] + adn;
            t = (t > 0.f) ? t : NEG_SLOPE * t;
            den += __expf(t - m);
        }
    }
#pragma unroll
    for (int off = 8; off >= 1; off >>= 1) den += __shfl_xor(den, off);
    float invden = 1.0f / den;

    // weighted scatter-max
    float acc[8];
#pragma unroll
    for (int j = 0; j < 8; j++) acc[j] = -INFINITY;
    int c0 = lane * 8;   // channel head == lane>>4 == head

    for (int e = 0; e < dn; e++) {
        int s = csr[base + e];
        float t = a_src[s * HEADS + head] + adn;
        t = (t > 0.f) ? t : NEG_SLOPE * t;
        float attn = __expf(t - m) * invden;
        bf16x8 hv = *(const bf16x8*)(h + (size_t)s * HC + c0);
#pragma unroll
        for (int j = 0; j < 8; j++)
            acc[j] = fmaxf(acc[j], bf2f((unsigned short)hv[j]) * attn);
    }

    bf16x8 ov;
#pragma unroll
    for (int j = 0; j < 8; j++) ov[j] = (short)f2bf(acc[j] + bias[c0 + j]);
    *(bf16x8*)(emb_sel + (size_t)w * HC + c0) = ov;
}

// ---------------------------------------------------------------------------
// bf16 MFMA GEMM:  C[m,o] = relu( sum_k A[m,k]*Wt[o,k] + bias[o] ) -> bf16
// 128x128 tile, BK=64, 256 threads, LDS rows padded to 72 shorts.
// ---------------------------------------------------------------------------
#define BK  64
#define LDK 72

template <bool RELU>
__global__ __launch_bounds__(256) void k_gemm(const unsigned short* __restrict__ A, int M,
                                              const unsigned short* __restrict__ Wt,
                                              const float* __restrict__ bias,
                                              unsigned short* __restrict__ C) {
    __shared__ unsigned short As[128 * LDK];
    __shared__ unsigned short Bs[128 * LDK];
    int tid = threadIdx.x;
    int m0 = blockIdx.y * 128;
    int o0 = blockIdx.x * 128;
    int wv = tid >> 6, lane = tid & 63;
    int wm = wv >> 1, wn = wv & 1;

    f32x4 acc[4][4];
#pragma unroll
    for (int i = 0; i < 4; i++)
#pragma unroll
        for (int j = 0; j < 4; j++) acc[i][j] = (f32x4){0.f, 0.f, 0.f, 0.f};

    bf16x8 ra[4], rb[4];
#pragma unroll
    for (int s = 0; s < 4; s++) {
        int c = s * 256 + tid;
        int row = c >> 3, col = (c & 7) * 8;
        int m = m0 + row;
        bf16x8 av = {0, 0, 0, 0, 0, 0, 0, 0};
        if (m < M) av = *(const bf16x8*)(A + (size_t)m * HC + col);
        ra[s] = av;
        rb[s] = *(const bf16x8*)(Wt + (size_t)(o0 + row) * HC + col);
    }

    for (int k0 = 0; k0 < HC; k0 += BK) {
        __syncthreads();
#pragma unroll
        for (int s = 0; s < 4; s++) {
            int c = s * 256 + tid;
            int row = c >> 3, col = (c & 7) * 8;
            *(bf16x8*)(&As[row * LDK + col]) = ra[s];
            *(bf16x8*)(&Bs[row * LDK + col]) = rb[s];
        }
        __syncthreads();

        int kn = k0 + BK;
        if (kn < HC) {
#pragma unroll
            for (int s = 0; s < 4; s++) {
                int c = s * 256 + tid;
                int row = c >> 3, col = (c & 7) * 8;
                int m = m0 + row;
                bf16x8 av = {0, 0, 0, 0, 0, 0, 0, 0};
                if (m < M) av = *(const bf16x8*)(A + (size_t)m * HC + kn + col);
                ra[s] = av;
                rb[s] = *(const bf16x8*)(Wt + (size_t)(o0 + row) * HC + kn + col);
            }
        }

#pragma unroll
        for (int kk = 0; kk < 2; kk++) {
            int kb = kk * 32 + (lane >> 4) * 8;
            bf16x8 af[4], bfr[4];
#pragma unroll
            for (int mi = 0; mi < 4; mi++)
                af[mi] = *(const bf16x8*)(&As[(wm * 64 + mi * 16 + (lane & 15)) * LDK + kb]);
#pragma unroll
            for (int ni = 0; ni < 4; ni++)
                bfr[ni] = *(const bf16x8*)(&Bs[(wn * 64 + ni * 16 + (lane & 15)) * LDK + kb]);
#pragma unroll
            for (int mi = 0; mi < 4; mi++)
#pragma unroll
                for (int ni = 0; ni < 4; ni++)
                    acc[mi][ni] = __builtin_amdgcn_mfma_f32_16x16x32_bf16(
                        af[mi], bfr[ni], acc[mi][ni], 0, 0, 0);
        }
    }

#pragma unroll
    for (int ni = 0; ni < 4; ni++) {
        int ncol = o0 + wn * 64 + ni * 16 + (lane & 15);
        float bv = bias[ncol];
#pragma unroll
        for (int mi = 0; mi < 4; mi++) {
            int mbase = m0 + wm * 64 + mi * 16 + (lane >> 4) * 4;
#pragma unroll
            for (int r = 0; r < 4; r++) {
                int m = mbase + r;
                if (m < M) {
                    float v = acc[mi][ni][r] + bv;
                    if (RELU) v = fmaxf(v, 0.f);
                    C[(size_t)m * HC + ncol] = f2bf(v);
                }
            }
        }
    }
}

// ---------------------------------------------------------------------------
// Final layer: out[m, 0..1] = tanh(h2[m] . W3[o] + b3[o]); one wave per row
// ---------------------------------------------------------------------------
__global__ void k_final(const unsigned short* __restrict__ h2, const float* __restrict__ W3,
                        const float* __restrict__ b3, float* __restrict__ out, int M) {
    int wave = threadIdx.x >> 6, lane = threadIdx.x & 63;
    int m = blockIdx.x * 4 + wave;
    if (m >= M) return;
    float s0 = 0.f, s1 = 0.f;
    bf16x8 hv = *(const bf16x8*)(h2 + (size_t)m * HC + lane * 8);
#pragma unroll
    for (int j = 0; j < 8; j++) {
        int k = lane * 8 + j;
        float v = bf2f((unsigned short)hv[j]);
        s0 += v * W3[k];
        s1 += v * W3[HC + k];
    }
#pragma unroll
    for (int off = 32; off >= 1; off >>= 1) {
        s0 += __shfl_xor(s0, off);
        s1 += __shfl_xor(s1, off);
    }
    if (lane == 0) {
        out[(size_t)m * 2 + 0] = tanhf(s0 + b3[0]);
        out[(size_t)m * 2 + 1] = tanhf(s1 + b3[1]);
    }
}

// ---------------------------------------------------------------------------
extern "C" void kernel_launch(void* const* d_in, const int* in_sizes, int n_in,
                              void* d_out, int out_size, void* d_ws, size_t ws_size,
                              hipStream_t stream) {
    const float* x       = (const float*)d_in[0];
    const int*   ei      = (const int*)d_in[1];
    const float* W       = (const float*)d_in[3];
    const float* att_src = (const float*)d_in[4];
    const float* att_dst = (const float*)d_in[5];
    const float* bias    = (const float*)d_in[6];
    const float* W1      = (const float*)d_in[7];
    const float* b1      = (const float*)d_in[8];
    const float* W2      = (const float*)d_in[9];
    const float* b2      = (const float*)d_in[10];
    const float* W3      = (const float*)d_in[11];
    const float* b3      = (const float*)d_in[12];
    float* out = (float*)d_out;

    char* ws = (char*)d_ws;
    unsigned short* h       = (unsigned short*)(ws);               // 51,200,000
    unsigned short* emb_sel = (unsigned short*)(ws + 51200000);    // 25,600,000
    unsigned short* h1      = (unsigned short*)(ws + 76800000);    // 25,600,000
    unsigned short* h2      = (unsigned short*)(ws + 102400000);   // 25,600,000
    unsigned short* W1b     = (unsigned short*)(ws + 128000000);   //    524,288
    unsigned short* W2b     = (unsigned short*)(ws + 128524288);   //    524,288
    float* a_src = (float*)(ws + 129048576);                       //    800,000
    float* a_dst = (float*)(ws + 129848576);                       //    800,000
    int*   deg   = (int*)  (ws + 130648576);                       //    200,000
    int*   offs  = (int*)  (ws + 130848576);                       //    200,000
    int*   curs  = (int*)  (ws + 131048576);                       //    200,000
    int*   bsum  = (int*)  (ws + 131248576);                       //      1,024
    int*   csr   = (int*)  (ws + 131249600);                       //  1,800,000  (~133 MB)

    k_cvt<<<256, 256, 0, stream>>>(W1, W1b, 65536);
    k_cvt<<<256, 256, 0, stream>>>(W2, W2b, 65536);
    k_transform<<<(N_NODES + 31) / 32, 256, 0, stream>>>(x, W, att_src, att_dst, h, a_src, a_dst);
    k_initdeg<<<(N_NODES + 255) / 256, 256, 0, stream>>>(deg);
    k_hist<<<(N_EDGES + 255) / 256, 256, 0, stream>>>(ei, deg);
    k_scan1<<<196, 256, 0, stream>>>(deg, offs, bsum);
    k_scan2<<<1, 64, 0, stream>>>(bsum, 196);
    k_scan3<<<196, 256, 0, stream>>>(offs, bsum);
    k_fill_self<<<(N_NODES + 255) / 256, 256, 0, stream>>>(offs, curs, csr);
    k_fill_edges<<<(N_EDGES + 255) / 256, 256, 0, stream>>>(ei, curs, csr);
    k_aggregate<<<6250, 256, 0, stream>>>(h, a_src, a_dst, csr, offs, deg, bias, emb_sel);

    dim3 g(4, 196);
    k_gemm<true><<<g, 256, 0, stream>>>(emb_sel, M_SEL, W1b, b1, h1);
    k_gemm<true><<<g, 256, 0, stream>>>(h1, M_SEL, W2b, b2, h2);
    k_final<<<(M_SEL + 3) / 4, 256, 0, stream>>>(h2, W3, b3, out, M_SEL);
}